// Round 9
// baseline (625.388 us; speedup 1.0000x reference)
//
#include <hip/hip_runtime.h>
#include <math.h>

#define D 512
#define N_TOK 4096
#define NHEAD 16
#define DH 32
#define DEPTH 3
#define MLPD 2048
#define GENES 250
#define GH 64
#define GW 64

typedef __attribute__((ext_vector_type(8))) short short8;
typedef __attribute__((ext_vector_type(4))) float f32x4;
typedef unsigned short ushort_t;

#define AS1 __attribute__((address_space(1)))
#define AS3 __attribute__((address_space(3)))

#if defined(__has_builtin)
#if __has_builtin(__builtin_amdgcn_exp2f)
#define EXP2F(x) __builtin_amdgcn_exp2f(x)
#endif
#endif
#ifndef EXP2F
#define EXP2F(x) __expf(0.69314718056f * (x))
#endif

__device__ __forceinline__ unsigned short f2bf(float f) {
  unsigned int u = __float_as_uint(f);
  u += 0x7fffu + ((u >> 16) & 1u);
  return (unsigned short)(u >> 16);
}
__device__ __forceinline__ unsigned int bfpack(float a, float b) {
  return __builtin_amdgcn_perm(__float_as_uint(b), __float_as_uint(a), 0x07060302u);
}
__device__ __forceinline__ void gload_lds16(const ushort_t* g, ushort_t* l) {
  __builtin_amdgcn_global_load_lds(
      (const AS1 unsigned int*)g,
      (AS3 unsigned int*)(unsigned int)(unsigned long long)l, 16, 0, 0);
}
// key permutation shared by the V^T store and the attention P-fragment
__device__ __forceinline__ int perm64(int m) {
  int mi = m >> 4, g = (m >> 2) & 3, r = m & 3;
  return ((mi & 1) << 5) | (g << 3) | ((mi >> 1) << 2) | r;
}

// ------------------------------- LayerNorm --------------------------------
__global__ __launch_bounds__(256) void ln_kernel(const float* __restrict__ x,
    const float* __restrict__ g, const float* __restrict__ b,
    float* __restrict__ yf, ushort_t* __restrict__ ybf) {
  int row = blockIdx.x;
  int t = threadIdx.x;
  const float* xr = x + (size_t)row * D;
  float v0 = xr[t], v1 = xr[t + 256];
  float s = v0 + v1;
  float sq = v0 * v0 + v1 * v1;
#pragma unroll
  for (int off = 32; off > 0; off >>= 1) {
    s += __shfl_down(s, off, 64);
    sq += __shfl_down(sq, off, 64);
  }
  __shared__ float s1[4], s2[4];
  int wid = t >> 6, lane = t & 63;
  if (lane == 0) { s1[wid] = s; s2[wid] = sq; }
  __syncthreads();
  float tot = s1[0] + s1[1] + s1[2] + s1[3];
  float totq = s2[0] + s2[1] + s2[2] + s2[3];
  float mean = tot * (1.0f / D);
  float var = totq * (1.0f / D) - mean * mean;
  float rs = rsqrtf(var + 1e-5f);
  float r0 = (v0 - mean) * rs * g[t] + b[t];
  float r1 = (v1 - mean) * rs * g[t + 256] + b[t + 256];
  if (yf) { yf[(size_t)row * D + t] = r0; yf[(size_t)row * D + t + 256] = r1; }
  if (ybf) {
    ybf[(size_t)row * D + t] = f2bf(r0);
    ybf[(size_t)row * D + t + 256] = f2bf(r1);
  }
}

// ---------------------------- bf16 MFMA GEMM -------------------------------
// R7 structure (best measured): tile TMxTN, BK=32*NKH, double-buffered LDS,
// prefetch of iter k+1 issued right after the barrier releasing the buffer.
// R14 (WIN, -13us): T1 XCD-aware block swizzle (bijective, nwg%8==0).
// R15 (small win, -5us): NKH bump (barrier-drain amortization).
// R16 (WIN, -12us): MLP1 -> 128x128; confirmed GEMM ceiling = LDS read pipe
// (MFMA-per-ds_read ratio). N=512 GEMMs (WO/MLP2) can't fatten: TN capped,
// TM=128 would drop to 1 block/CU.
// R17: split-K for WO/MLP2 (mode 3). gridDim.z=2 K-slices; epilogue
// atomicAdd into x (x already holds the residual; bias added by z==0 only).
// Residency 2->4 blocks/CU (NKH=2, LDS 32KB). Atomics are device-scope by
// default; both z-slices share an XCD (swizzle ignores z) -> L2-local RMW.
// mode 0: fp32 C (+res). mode 1: gelu -> Cbf. mode 2: qkv. mode 3: split-K.
template <int TM, int TN, int NKH>
__global__ __launch_bounds__(256) void gemm_bf(
    const ushort_t* __restrict__ A, const ushort_t* __restrict__ B,
    const float* __restrict__ bias, const float* __restrict__ res,
    float* __restrict__ C, ushort_t* __restrict__ Cbf,
    ushort_t* __restrict__ qO, ushort_t* __restrict__ kO, ushort_t* __restrict__ vO,
    int K, int ldc, int nstore, int mode) {
  constexpr int MI = TM / 32;
  constexpr int NI = TN / 32;
  __shared__ ushort_t As[2][NKH][TM * 32];
  __shared__ ushort_t Bs[2][NKH][TN * 32];
  int t = threadIdx.x;
  int w = t >> 6, lane = t & 63;
  int g = lane >> 4, c = lane & 15;
  // T1 XCD swizzle: work-id chunking so consecutive tiles share an XCD L2
  int orig = blockIdx.y * gridDim.x + blockIdx.x;
  int cpx = (gridDim.x * gridDim.y) >> 3;
  int wid2 = (orig & 7) * cpx + (orig >> 3);
  int bn = (wid2 % gridDim.x) * TN;
  int bm = (wid2 / gridDim.x) * TM;
  int wr = (w >> 1) * (TM / 2);
  int wc = (w & 1) * (TN / 2);

  // split-K: K is the per-slice depth; full row stride = K * gridDim.z
  const size_t Kld = (size_t)K * gridDim.z;
  const int koff0 = blockIdx.z * K;

  const ushort_t* gA = A + (size_t)(bm + (t >> 2)) * Kld + koff0 + (t & 3) * 8;
  const ushort_t* gB = B + (size_t)(bn + (t >> 2)) * Kld + koff0 + (t & 3) * 8;

  auto stage = [&](int p, int koff) {
#pragma unroll
    for (int h = 0; h < NKH; ++h) {
      gload_lds16(gA + koff + h * 32, &As[p][h][t * 8]);
      if (TM == 128)
        gload_lds16(gA + koff + h * 32 + (size_t)64 * Kld, &As[p][h][(t + 256) * 8]);
      gload_lds16(gB + koff + h * 32, &Bs[p][h][t * 8]);
      if (TN == 128)
        gload_lds16(gB + koff + h * 32 + (size_t)64 * Kld, &Bs[p][h][(t + 256) * 8]);
    }
  };

  f32x4 acc[MI][NI] = {};

  const int niter = K / (32 * NKH);
  stage(0, 0);
  __syncthreads();
  for (int it = 0; it < niter; ++it) {
    int p = it & 1;
    if (it + 1 < niter) stage(p ^ 1, (it + 1) * 32 * NKH);  // prefetch overlaps compute
#pragma unroll
    for (int kh = 0; kh < NKH; ++kh) {
      short8 af[MI], bfr[NI];
#pragma unroll
      for (int mi = 0; mi < MI; ++mi)
        af[mi] = *(const short8*)&As[p][kh][(wr + mi * 16 + c) * 32 + g * 8];
#pragma unroll
      for (int ni = 0; ni < NI; ++ni)
        bfr[ni] = *(const short8*)&Bs[p][kh][(wc + ni * 16 + c) * 32 + g * 8];
#pragma unroll
      for (int mi = 0; mi < MI; ++mi)
#pragma unroll
        for (int ni = 0; ni < NI; ++ni)
          acc[mi][ni] = __builtin_amdgcn_mfma_f32_16x16x32_bf16(
              af[mi], bfr[ni], acc[mi][ni], 0, 0, 0);
    }
    __syncthreads();
  }

  const float qs_scale = 0.17677669529663688f * 1.4426950408889634f;
  if (mode == 2) {
#pragma unroll
    for (int ni = 0; ni < NI; ++ni) {
      int col = bn + wc + ni * 16 + c;
      float bv = bias[col];
      int which = col >> 9;
      int h = (col >> 5) & 15;
      int d = col & 31;
      size_t hb = (size_t)h * (N_TOK * DH);
#pragma unroll
      for (int mi = 0; mi < MI; ++mi) {
        int row0 = bm + wr + mi * 16 + g * 4;
        float v0 = acc[mi][ni][0] + bv;
        float v1 = acc[mi][ni][1] + bv;
        float v2 = acc[mi][ni][2] + bv;
        float v3 = acc[mi][ni][3] + bv;
        if (which == 0) {
          qO[hb + (size_t)(row0 + 0) * DH + d] = f2bf(v0 * qs_scale);
          qO[hb + (size_t)(row0 + 1) * DH + d] = f2bf(v1 * qs_scale);
          qO[hb + (size_t)(row0 + 2) * DH + d] = f2bf(v2 * qs_scale);
          qO[hb + (size_t)(row0 + 3) * DH + d] = f2bf(v3 * qs_scale);
        } else if (which == 1) {
          kO[hb + (size_t)(row0 + 0) * DH + d] = f2bf(v0);
          kO[hb + (size_t)(row0 + 1) * DH + d] = f2bf(v1);
          kO[hb + (size_t)(row0 + 2) * DH + d] = f2bf(v2);
          kO[hb + (size_t)(row0 + 3) * DH + d] = f2bf(v3);
        } else {
          int m = row0 & 63;
          int mi_l = m >> 4, g_l = (m >> 2) & 3;
          int nb = ((mi_l & 1) << 5) | (g_l << 3) | ((mi_l >> 1) << 2);
          uint2 pk;
          pk.x = (unsigned)f2bf(v0) | ((unsigned)f2bf(v1) << 16);
          pk.y = (unsigned)f2bf(v2) | ((unsigned)f2bf(v3) << 16);
          *(uint2*)(vO + hb + (size_t)d * N_TOK + (row0 & ~63) + nb) = pk;
        }
      }
    }
    return;
  }
  if (mode == 3) {
    // split-K accumulate: x already holds the residual; z==0 adds bias
    bool addb = (blockIdx.z == 0);
#pragma unroll
    for (int ni = 0; ni < NI; ++ni) {
      int col = bn + wc + ni * 16 + c;
      float bv = addb ? bias[col] : 0.f;
#pragma unroll
      for (int mi = 0; mi < MI; ++mi) {
        int row0 = bm + wr + mi * 16 + g * 4;
#pragma unroll
        for (int reg = 0; reg < 4; ++reg) {
          size_t idx = (size_t)(row0 + reg) * ldc + col;
          atomicAdd(&C[idx], acc[mi][ni][reg] + bv);
        }
      }
    }
    return;
  }
#pragma unroll
  for (int ni = 0; ni < NI; ++ni) {
    int col = bn + wc + ni * 16 + c;
    float bv = bias[col];
    bool cok = col < nstore;
#pragma unroll
    for (int mi = 0; mi < MI; ++mi) {
      int row0 = bm + wr + mi * 16 + g * 4;
#pragma unroll
      for (int reg = 0; reg < 4; ++reg) {
        int row = row0 + reg;
        float v = acc[mi][ni][reg] + bv;
        if (mode == 0) {
          size_t idx = (size_t)row * ldc + col;
          if (cok) {
            if (res) v += res[idx];
            C[idx] = v;
          }
        } else {
          v = 0.5f * v * (1.0f + erff(v * 0.70710678118654752f));
          Cbf[(size_t)row * ldc + col] = f2bf(v);
        }
      }
    }
  }
}

// --------------------------- MFMA flash attention --------------------------
// R7 version verbatim (proven best: ~62 us/layer). Ledger of structural
// alternatives, all regressed or neutral: R10 smaller q-tile/2x waves
// (69.2 — LDS pipe throttles), R11 K via VMEM (70.6 — barrier drains vmcnt),
// R12 full dbuf + 1 barrier/tile + QK/PV software pipeline (62.3 — neutral),
// R13 zero-LDS register pipeline (77.2 — VMEM latency exposed at 4 waves/CU).
// The structure is balanced: exp VALU floor ~27us, LDS ~15us, MFMA ~17us
// with 2 waves/SIMD overlap. Do not re-open without a new mechanism.
#define KST 40   // Ks row stride (ushorts)
#define VTST 72  // Vts row stride (ushorts)

__global__ __launch_bounds__(256) void attn_mfma(
    const ushort_t* __restrict__ qb, const ushort_t* __restrict__ kb,
    const ushort_t* __restrict__ vtb, ushort_t* __restrict__ ao) {
  __shared__ ushort_t Ks[64 * KST];
  __shared__ ushort_t Vts[32 * VTST];
  int qt = blockIdx.x, head = blockIdx.y;
  int t = threadIdx.x;
  int w = t >> 6, lane = t & 63;
  int g = lane >> 4, c = lane & 15;
  const size_t hbase = (size_t)head * (N_TOK * DH);
  int q0 = qt * 128 + w * 32;

  short8 qf[2];
  qf[0] = *(const short8*)(qb + hbase + (size_t)(q0 + c) * DH + g * 8);
  qf[1] = *(const short8*)(qb + hbase + (size_t)(q0 + 16 + c) * DH + g * 8);

  short8 ones;
#pragma unroll
  for (int i = 0; i < 8; ++i) ones[i] = (short)0x3F80;

  f32x4 o[2][2] = {};
  f32x4 lf[2] = {};
  const f32x4 zf = {0.f, 0.f, 0.f, 0.f};

  const ushort_t* kg = kb + hbase + (size_t)(t >> 2) * DH + (t & 3) * 8;
  const ushort_t* vg = vtb + hbase + (size_t)(t >> 3) * N_TOK + (t & 7) * 8;
  ushort_t* kw = &Ks[(t >> 2) * KST + (t & 3) * 8];
  ushort_t* vw = &Vts[(t >> 3) * VTST + (t & 7) * 8];

  short8 kreg = *(const short8*)kg;
  short8 vreg = *(const short8*)vg;

  typedef union { short8 s8; unsigned int u32[4]; } pk_t;

  for (int tile = 0; tile < N_TOK / 64; ++tile) {
    __syncthreads();
    *(short8*)kw = kreg;
    *(short8*)vw = vreg;
    __syncthreads();
    if (tile + 1 < N_TOK / 64) {
      kreg = *(const short8*)(kg + (size_t)(tile + 1) * 64 * DH);
      vreg = *(const short8*)(vg + (tile + 1) * 64);
    }

    short8 kf[4];
#pragma unroll
    for (int mi = 0; mi < 4; ++mi)
      kf[mi] = *(const short8*)&Ks[(mi * 16 + c) * KST + g * 8];
    short8 vf[2][2];
#pragma unroll
    for (int half = 0; half < 2; ++half)
#pragma unroll
      for (int ch = 0; ch < 2; ++ch)
        vf[half][ch] = *(const short8*)&Vts[(half * 16 + c) * VTST + ch * 32 + g * 8];

    short8 pf[2][2];
#pragma unroll
    for (int qs = 0; qs < 2; ++qs) {
      f32x4 sp[4];
#pragma unroll
      for (int mi = 0; mi < 4; ++mi)
        sp[mi] = __builtin_amdgcn_mfma_f32_16x16x32_bf16(kf[mi], qf[qs], zf, 0, 0, 0);
      float pr[4][4];
#pragma unroll
      for (int mi = 0; mi < 4; ++mi)
#pragma unroll
        for (int r = 0; r < 4; ++r) pr[mi][r] = EXP2F(sp[mi][r]);
      pk_t p0, p1;
      p0.u32[0] = bfpack(pr[0][0], pr[0][1]);
      p0.u32[1] = bfpack(pr[0][2], pr[0][3]);
      p0.u32[2] = bfpack(pr[2][0], pr[2][1]);
      p0.u32[3] = bfpack(pr[2][2], pr[2][3]);
      p1.u32[0] = bfpack(pr[1][0], pr[1][1]);
      p1.u32[1] = bfpack(pr[1][2], pr[1][3]);
      p1.u32[2] = bfpack(pr[3][0], pr[3][1]);
      p1.u32[3] = bfpack(pr[3][2], pr[3][3]);
      pf[qs][0] = p0.s8;
      pf[qs][1] = p1.s8;
    }

#pragma unroll
    for (int qs = 0; qs < 2; ++qs) {
#pragma unroll
      for (int ch = 0; ch < 2; ++ch) {
        lf[qs] = __builtin_amdgcn_mfma_f32_16x16x32_bf16(ones, pf[qs][ch], lf[qs], 0, 0, 0);
#pragma unroll
        for (int half = 0; half < 2; ++half)
          o[qs][half] = __builtin_amdgcn_mfma_f32_16x16x32_bf16(
              vf[half][ch], pf[qs][ch], o[qs][half], 0, 0, 0);
      }
    }
  }

#pragma unroll
  for (int qs = 0; qs < 2; ++qs) {
    float inv = 1.0f / lf[qs][0];
    int q = q0 + qs * 16 + c;
    ushort_t* op = ao + (size_t)q * D + head * DH;
#pragma unroll
    for (int half = 0; half < 2; ++half)
#pragma unroll
      for (int reg = 0; reg < 4; ++reg)
        op[half * 16 + g * 4 + reg] = f2bf(o[qs][half][reg] * inv);
  }
}

// ------------------------- depthwise conv + next-LN ------------------------
__global__ void scatter_kernel(const int* __restrict__ coords,
                               int* __restrict__ pos2tok) {
  int n = blockIdx.x * 256 + threadIdx.x;
  if (n < N_TOK) pos2tok[coords[2 * n] * GW + coords[2 * n + 1]] = n;
}

__global__ __launch_bounds__(256) void conv_ln_kernel(
    const float* __restrict__ xin, float* __restrict__ xout,
    const float* __restrict__ ck, const float* __restrict__ cb,
    const int* __restrict__ pos2tok, const int* __restrict__ coords,
    const float* __restrict__ g, const float* __restrict__ b,
    float* __restrict__ yf, ushort_t* __restrict__ ybf) {
  int n = blockIdx.x, t = threadIdx.x;
  __shared__ int nb[9];
  if (t < 9) {
    int r = coords[2 * n], c = coords[2 * n + 1];
    int dy = t / 3 - 1, dx = t % 3 - 1;
    int rr = r + dy, cc = c + dx;
    nb[t] = (rr >= 0 && rr < GH && cc >= 0 && cc < GW) ? pos2tok[rr * GW + cc] : -1;
  }
  __syncthreads();
  float v[2];
#pragma unroll
  for (int j = 0; j < 2; ++j) {
    int ch = t + j * 256;
    float s = cb[ch];
#pragma unroll
    for (int tap = 0; tap < 9; ++tap) {
      int tok = nb[tap];
      if (tok >= 0) s = fmaf(ck[ch * 9 + tap], xin[(size_t)tok * D + ch], s);
    }
    v[j] = xin[(size_t)n * D + ch] + s;
    xout[(size_t)n * D + ch] = v[j];
  }
  float s = v[0] + v[1];
  float sq = v[0] * v[0] + v[1] * v[1];
#pragma unroll
  for (int off = 32; off > 0; off >>= 1) {
    s += __shfl_down(s, off, 64);
    sq += __shfl_down(sq, off, 64);
  }
  __shared__ float s1[4], s2[4];
  int wid = t >> 6, lane = t & 63;
  if (lane == 0) { s1[wid] = s; s2[wid] = sq; }
  __syncthreads();
  float tot = s1[0] + s1[1] + s1[2] + s1[3];
  float totq = s2[0] + s2[1] + s2[2] + s2[3];
  float mean = tot * (1.0f / D);
  float var = totq * (1.0f / D) - mean * mean;
  float rs = rsqrtf(var + 1e-5f);
  float r0 = (v[0] - mean) * rs * g[t] + b[t];
  float r1 = (v[1] - mean) * rs * g[t + 256] + b[t + 256];
  if (yf) { yf[(size_t)n * D + t] = r0; yf[(size_t)n * D + t + 256] = r1; }
  ybf[(size_t)n * D + t] = f2bf(r0);
  ybf[(size_t)n * D + t + 256] = f2bf(r1);
}

// ------------------------ weight cast (fp32->bf16, pad) --------------------
__global__ __launch_bounds__(256) void castw(const float* __restrict__ src,
    ushort_t* __restrict__ dst, int n_src, int n_dst) {
  int i = (blockIdx.x * 256 + threadIdx.x) * 4;
  if (i >= n_dst) return;
  unsigned long long pk = 0;
#pragma unroll
  for (int j = 0; j < 4; ++j) {
    float v = (i + j < n_src) ? src[i + j] : 0.f;
    pk |= ((unsigned long long)f2bf(v)) << (16 * j);
  }
  *(unsigned long long*)(dst + i) = pk;
}

__global__ void pad_bias(const float* __restrict__ src, float* __restrict__ dst) {
  int i = threadIdx.x;
  dst[i] = (i < GENES) ? src[i] : 0.f;
}

// ------------------------------- launch ------------------------------------
extern "C" void kernel_launch(void* const* d_in, const int* in_sizes, int n_in,
                              void* d_out, int out_size, void* d_ws, size_t ws_size,
                              hipStream_t stream) {
  const float* gf     = (const float*)d_in[0];
  const int*   coords = (const int*)d_in[1];
  const float* ln1_g  = (const float*)d_in[4];
  const float* ln1_b  = (const float*)d_in[5];
  const float* wqkv   = (const float*)d_in[6];
  const float* bqkv   = (const float*)d_in[7];
  const float* wo     = (const float*)d_in[8];
  const float* bo     = (const float*)d_in[9];
  const float* ln2_g  = (const float*)d_in[10];
  const float* ln2_b  = (const float*)d_in[11];
  const float* w1     = (const float*)d_in[12];
  const float* b1     = (const float*)d_in[13];
  const float* w2     = (const float*)d_in[14];
  const float* b2     = (const float*)d_in[15];
  const float* ck     = (const float*)d_in[16];
  const float* cb     = (const float*)d_in[17];
  const float* lnf_g  = (const float*)d_in[18];
  const float* lnf_b  = (const float*)d_in[19];
  const float* wp     = (const float*)d_in[20];
  const float* bp     = (const float*)d_in[21];
  float* out = (float*)d_out;

  const size_t ND = (size_t)N_TOK * D;
  float* xb0 = (float*)d_ws;
  float* xb1 = xb0 + ND;
  ushort_t* xn_bf  = (ushort_t*)(xb1 + ND);      // ND
  ushort_t* ao_bf  = xn_bf + ND;                 // ND
  ushort_t* out_bf = ao_bf + ND;                 // ND
  ushort_t* shared = out_bf + ND;                // max(3*ND, N*MLPD)
  ushort_t* qb   = shared;
  ushort_t* kbuf = qb + ND;
  ushort_t* vtb  = kbuf + ND;
  ushort_t* h_bf = shared;                       // aliases qkv bufs (disjoint lifetime)
  ushort_t* wqkv_bf = shared + (size_t)N_TOK * MLPD;
  ushort_t* wo_bf = wqkv_bf + DEPTH * 3 * D * D;
  ushort_t* w1_bf = wo_bf + DEPTH * D * D;
  ushort_t* w2_bf = w1_bf + DEPTH * MLPD * D;
  ushort_t* wp_bf = w2_bf + DEPTH * D * MLPD;
  float* bp_pad = (float*)(wp_bf + 256 * D);
  int* pos2tok = (int*)(bp_pad + 256);

  hipMemcpyAsync(xb0, gf, ND * sizeof(float), hipMemcpyDeviceToDevice, stream);
  hipMemsetAsync(pos2tok, 0xFF, GH * GW * sizeof(int), stream);
  scatter_kernel<<<(N_TOK + 255) / 256, 256, 0, stream>>>(coords, pos2tok);

  int nw;
  nw = DEPTH * 3 * D * D;  castw<<<(nw / 4 + 255) / 256, 256, 0, stream>>>(wqkv, wqkv_bf, nw, nw);
  nw = DEPTH * D * D;      castw<<<(nw / 4 + 255) / 256, 256, 0, stream>>>(wo, wo_bf, nw, nw);
  nw = DEPTH * MLPD * D;   castw<<<(nw / 4 + 255) / 256, 256, 0, stream>>>(w1, w1_bf, nw, nw);
  nw = DEPTH * D * MLPD;   castw<<<(nw / 4 + 255) / 256, 256, 0, stream>>>(w2, w2_bf, nw, nw);
  castw<<<(256 * D / 4 + 255) / 256, 256, 0, stream>>>(wp, wp_bf, GENES * D, 256 * D);
  pad_bias<<<1, 256, 0, stream>>>(bp, bp_pad);

  // ln1 of layer 0 (subsequent ln1/lnf are fused into conv_ln)
  ln_kernel<<<N_TOK, 256, 0, stream>>>(xb0, ln1_g, ln1_b, nullptr, xn_bf);

  float* x  = xb0;
  float* xo = xb1;
  for (int i = 0; i < DEPTH; ++i) {
    // QKV: 128x64 tile, BK=64 -> 768 blocks = 3 blocks/CU (LDS 48KB)
    gemm_bf<128, 64, 2><<<dim3(24, 32), 256, 0, stream>>>(
        xn_bf, wqkv_bf + (size_t)i * 3 * D * D, bqkv + (size_t)i * 3 * D,
        nullptr, nullptr, nullptr, qb, kbuf, vtb, D, 0, 3 * D, 2);
    attn_mfma<<<dim3(N_TOK / 128, NHEAD), 256, 0, stream>>>(qb, kbuf, vtb, ao_bf);
    // WO: split-K x2 (slice K=256) -> 1024 blocks = 4 blocks/CU; atomic +=
    gemm_bf<64, 64, 2><<<dim3(8, 64, 2), 256, 0, stream>>>(
        ao_bf, wo_bf + (size_t)i * D * D, bo + (size_t)i * D,
        nullptr, x, nullptr, nullptr, nullptr, nullptr, D / 2, D, D, 3);
    ln_kernel<<<N_TOK, 256, 0, stream>>>(x, ln2_g + i * D, ln2_b + i * D, nullptr, xn_bf);
    // MLP1: 128x128 tile, BK=64 -> 512 blocks = 2 blocks/CU (LDS 64KB, cap 2)
    gemm_bf<128, 128, 2><<<dim3(16, 32), 256, 0, stream>>>(
        xn_bf, w1_bf + (size_t)i * MLPD * D, b1 + (size_t)i * MLPD,
        nullptr, nullptr, h_bf, nullptr, nullptr, nullptr, D, MLPD, MLPD, 1);
    // MLP2: split-K x2 (slice K=1024) -> 1024 blocks = 4 blocks/CU; atomic +=
    gemm_bf<64, 64, 2><<<dim3(8, 64, 2), 256, 0, stream>>>(
        h_bf, w2_bf + (size_t)i * D * MLPD, b2 + (size_t)i * D,
        nullptr, x, nullptr, nullptr, nullptr, nullptr, MLPD / 2, D, D, 3);
    if (i < DEPTH - 1) {
      conv_ln_kernel<<<N_TOK, 256, 0, stream>>>(
          x, xo, ck + (size_t)i * D * 9, cb + (size_t)i * D, pos2tok, coords,
          ln1_g + (i + 1) * D, ln1_b + (i + 1) * D, nullptr, xn_bf);
    } else {
      conv_ln_kernel<<<N_TOK, 256, 0, stream>>>(
          x, xo, ck + (size_t)i * D * 9, cb + (size_t)i * D, pos2tok, coords,
          lnf_g, lnf_b, out, out_bf);
    }
    float* tmp = x; x = xo; xo = tmp;
  }
  gemm_bf<64, 64, 2><<<dim3(4, 64), 256, 0, stream>>>(
      out_bf, wp_bf, bp_pad, nullptr, out + ND, nullptr, nullptr, nullptr, nullptr,
      D, GENES, GENES, 0);
}

// Round 10
// 602.454 us; speedup vs baseline: 1.0381x; 1.0381x over previous
//
#include <hip/hip_runtime.h>
#include <math.h>

#define D 512
#define N_TOK 4096
#define NHEAD 16
#define DH 32
#define DEPTH 3
#define MLPD 2048
#define GENES 250
#define GH 64
#define GW 64

typedef __attribute__((ext_vector_type(8))) short short8;
typedef __attribute__((ext_vector_type(4))) float f32x4;
typedef unsigned short ushort_t;

#define AS1 __attribute__((address_space(1)))
#define AS3 __attribute__((address_space(3)))

#if defined(__has_builtin)
#if __has_builtin(__builtin_amdgcn_exp2f)
#define EXP2F(x) __builtin_amdgcn_exp2f(x)
#endif
#endif
#ifndef EXP2F
#define EXP2F(x) __expf(0.69314718056f * (x))
#endif

__device__ __forceinline__ unsigned short f2bf(float f) {
  unsigned int u = __float_as_uint(f);
  u += 0x7fffu + ((u >> 16) & 1u);
  return (unsigned short)(u >> 16);
}
__device__ __forceinline__ unsigned int bfpack(float a, float b) {
  return __builtin_amdgcn_perm(__float_as_uint(b), __float_as_uint(a), 0x07060302u);
}
__device__ __forceinline__ void gload_lds16(const ushort_t* g, ushort_t* l) {
  __builtin_amdgcn_global_load_lds(
      (const AS1 unsigned int*)g,
      (AS3 unsigned int*)(unsigned int)(unsigned long long)l, 16, 0, 0);
}
// key permutation shared by the V^T store and the attention P-fragment
__device__ __forceinline__ int perm64(int m) {
  int mi = m >> 4, g = (m >> 2) & 3, r = m & 3;
  return ((mi & 1) << 5) | (g << 3) | ((mi >> 1) << 2) | r;
}

// ------------------------------- LayerNorm --------------------------------
__global__ __launch_bounds__(256) void ln_kernel(const float* __restrict__ x,
    const float* __restrict__ g, const float* __restrict__ b,
    float* __restrict__ yf, ushort_t* __restrict__ ybf) {
  int row = blockIdx.x;
  int t = threadIdx.x;
  const float* xr = x + (size_t)row * D;
  float v0 = xr[t], v1 = xr[t + 256];
  float s = v0 + v1;
  float sq = v0 * v0 + v1 * v1;
#pragma unroll
  for (int off = 32; off > 0; off >>= 1) {
    s += __shfl_down(s, off, 64);
    sq += __shfl_down(sq, off, 64);
  }
  __shared__ float s1[4], s2[4];
  int wid = t >> 6, lane = t & 63;
  if (lane == 0) { s1[wid] = s; s2[wid] = sq; }
  __syncthreads();
  float tot = s1[0] + s1[1] + s1[2] + s1[3];
  float totq = s2[0] + s2[1] + s2[2] + s2[3];
  float mean = tot * (1.0f / D);
  float var = totq * (1.0f / D) - mean * mean;
  float rs = rsqrtf(var + 1e-5f);
  float r0 = (v0 - mean) * rs * g[t] + b[t];
  float r1 = (v1 - mean) * rs * g[t + 256] + b[t + 256];
  if (yf) { yf[(size_t)row * D + t] = r0; yf[(size_t)row * D + t + 256] = r1; }
  if (ybf) {
    ybf[(size_t)row * D + t] = f2bf(r0);
    ybf[(size_t)row * D + t + 256] = f2bf(r1);
  }
}

// ---------------------------- bf16 MFMA GEMM -------------------------------
// R7 structure (best measured): tile TMxTN, BK=32*NKH, double-buffered LDS,
// prefetch of iter k+1 issued right after the barrier releasing the buffer.
// R14 (WIN, -13us): T1 XCD-aware block swizzle (bijective, nwg%8==0).
// R15 (small win, -5us): NKH bump (barrier-drain amortization).
// R16 (WIN, -12us): MLP1 -> 128x128; confirmed GEMM ceiling = LDS read pipe
// (MFMA-per-ds_read ratio).
// R17 (REGRESSED +33us, reverted): split-K w/ atomicAdd epilogue — 2M
// same-address L2 RMWs serialized; residency gain swamped. Split-K via
// atomics is off the table for these shapes.
// R18: QKV -> 128x96 (TN=96, NI=3): 12 MFMA / 7 ds_read = 1.71 ratio
// (was 1.33). Grid (16,32)=512=2/CU; LDS 56KB -> cap 2/CU. Staging: extra
// half-grid B-load by waves 0-1 (wave-uniform branch) for rows 64..95.
// mode 0: fp32 C (+res). mode 1: gelu -> Cbf. mode 2: qkv. mode 3: split-K
// (dead since R17 revert; kept for template stability).
template <int TM, int TN, int NKH>
__global__ __launch_bounds__(256) void gemm_bf(
    const ushort_t* __restrict__ A, const ushort_t* __restrict__ B,
    const float* __restrict__ bias, const float* __restrict__ res,
    float* __restrict__ C, ushort_t* __restrict__ Cbf,
    ushort_t* __restrict__ qO, ushort_t* __restrict__ kO, ushort_t* __restrict__ vO,
    int K, int ldc, int nstore, int mode) {
  constexpr int MI = TM / 32;
  constexpr int NI = TN / 32;
  __shared__ ushort_t As[2][NKH][TM * 32];
  __shared__ ushort_t Bs[2][NKH][TN * 32];
  int t = threadIdx.x;
  int w = t >> 6, lane = t & 63;
  int g = lane >> 4, c = lane & 15;
  // T1 XCD swizzle: work-id chunking so consecutive tiles share an XCD L2
  int orig = blockIdx.y * gridDim.x + blockIdx.x;
  int cpx = (gridDim.x * gridDim.y) >> 3;
  int wid2 = (orig & 7) * cpx + (orig >> 3);
  int bn = (wid2 % gridDim.x) * TN;
  int bm = (wid2 / gridDim.x) * TM;
  int wr = (w >> 1) * (TM / 2);
  int wc = (w & 1) * (TN / 2);

  // split-K generality: K is per-slice depth; full row stride = K * gridDim.z
  const size_t Kld = (size_t)K * gridDim.z;
  const int koff0 = blockIdx.z * K;

  const ushort_t* gA = A + (size_t)(bm + (t >> 2)) * Kld + koff0 + (t & 3) * 8;
  const ushort_t* gB = B + (size_t)(bn + (t >> 2)) * Kld + koff0 + (t & 3) * 8;

  auto stage = [&](int p, int koff) {
#pragma unroll
    for (int h = 0; h < NKH; ++h) {
      gload_lds16(gA + koff + h * 32, &As[p][h][t * 8]);
      if (TM == 128)
        gload_lds16(gA + koff + h * 32 + (size_t)64 * Kld, &As[p][h][(t + 256) * 8]);
      gload_lds16(gB + koff + h * 32, &Bs[p][h][t * 8]);
      if (TN == 128)
        gload_lds16(gB + koff + h * 32 + (size_t)64 * Kld, &Bs[p][h][(t + 256) * 8]);
      if (TN == 96 && t < 128)  // rows 64..95 (waves 0-1, wave-uniform)
        gload_lds16(gB + koff + h * 32 + (size_t)64 * Kld, &Bs[p][h][(t + 256) * 8]);
    }
  };

  f32x4 acc[MI][NI] = {};

  const int niter = K / (32 * NKH);
  stage(0, 0);
  __syncthreads();
  for (int it = 0; it < niter; ++it) {
    int p = it & 1;
    if (it + 1 < niter) stage(p ^ 1, (it + 1) * 32 * NKH);  // prefetch overlaps compute
#pragma unroll
    for (int kh = 0; kh < NKH; ++kh) {
      short8 af[MI], bfr[NI];
#pragma unroll
      for (int mi = 0; mi < MI; ++mi)
        af[mi] = *(const short8*)&As[p][kh][(wr + mi * 16 + c) * 32 + g * 8];
#pragma unroll
      for (int ni = 0; ni < NI; ++ni)
        bfr[ni] = *(const short8*)&Bs[p][kh][(wc + ni * 16 + c) * 32 + g * 8];
#pragma unroll
      for (int mi = 0; mi < MI; ++mi)
#pragma unroll
        for (int ni = 0; ni < NI; ++ni)
          acc[mi][ni] = __builtin_amdgcn_mfma_f32_16x16x32_bf16(
              af[mi], bfr[ni], acc[mi][ni], 0, 0, 0);
    }
    __syncthreads();
  }

  const float qs_scale = 0.17677669529663688f * 1.4426950408889634f;
  if (mode == 2) {
#pragma unroll
    for (int ni = 0; ni < NI; ++ni) {
      int col = bn + wc + ni * 16 + c;
      float bv = bias[col];
      int which = col >> 9;
      int h = (col >> 5) & 15;
      int d = col & 31;
      size_t hb = (size_t)h * (N_TOK * DH);
#pragma unroll
      for (int mi = 0; mi < MI; ++mi) {
        int row0 = bm + wr + mi * 16 + g * 4;
        float v0 = acc[mi][ni][0] + bv;
        float v1 = acc[mi][ni][1] + bv;
        float v2 = acc[mi][ni][2] + bv;
        float v3 = acc[mi][ni][3] + bv;
        if (which == 0) {
          qO[hb + (size_t)(row0 + 0) * DH + d] = f2bf(v0 * qs_scale);
          qO[hb + (size_t)(row0 + 1) * DH + d] = f2bf(v1 * qs_scale);
          qO[hb + (size_t)(row0 + 2) * DH + d] = f2bf(v2 * qs_scale);
          qO[hb + (size_t)(row0 + 3) * DH + d] = f2bf(v3 * qs_scale);
        } else if (which == 1) {
          kO[hb + (size_t)(row0 + 0) * DH + d] = f2bf(v0);
          kO[hb + (size_t)(row0 + 1) * DH + d] = f2bf(v1);
          kO[hb + (size_t)(row0 + 2) * DH + d] = f2bf(v2);
          kO[hb + (size_t)(row0 + 3) * DH + d] = f2bf(v3);
        } else {
          int m = row0 & 63;
          int mi_l = m >> 4, g_l = (m >> 2) & 3;
          int nb = ((mi_l & 1) << 5) | (g_l << 3) | ((mi_l >> 1) << 2);
          uint2 pk;
          pk.x = (unsigned)f2bf(v0) | ((unsigned)f2bf(v1) << 16);
          pk.y = (unsigned)f2bf(v2) | ((unsigned)f2bf(v3) << 16);
          *(uint2*)(vO + hb + (size_t)d * N_TOK + (row0 & ~63) + nb) = pk;
        }
      }
    }
    return;
  }
  if (mode == 3) {
    bool addb = (blockIdx.z == 0);
#pragma unroll
    for (int ni = 0; ni < NI; ++ni) {
      int col = bn + wc + ni * 16 + c;
      float bv = addb ? bias[col] : 0.f;
#pragma unroll
      for (int mi = 0; mi < MI; ++mi) {
        int row0 = bm + wr + mi * 16 + g * 4;
#pragma unroll
        for (int reg = 0; reg < 4; ++reg) {
          size_t idx = (size_t)(row0 + reg) * ldc + col;
          atomicAdd(&C[idx], acc[mi][ni][reg] + bv);
        }
      }
    }
    return;
  }
#pragma unroll
  for (int ni = 0; ni < NI; ++ni) {
    int col = bn + wc + ni * 16 + c;
    float bv = bias[col];
    bool cok = col < nstore;
#pragma unroll
    for (int mi = 0; mi < MI; ++mi) {
      int row0 = bm + wr + mi * 16 + g * 4;
#pragma unroll
      for (int reg = 0; reg < 4; ++reg) {
        int row = row0 + reg;
        float v = acc[mi][ni][reg] + bv;
        if (mode == 0) {
          size_t idx = (size_t)row * ldc + col;
          if (cok) {
            if (res) v += res[idx];
            C[idx] = v;
          }
        } else {
          v = 0.5f * v * (1.0f + erff(v * 0.70710678118654752f));
          Cbf[(size_t)row * ldc + col] = f2bf(v);
        }
      }
    }
  }
}

// --------------------------- MFMA flash attention --------------------------
// R7 version verbatim (proven best: ~62 us/layer). Ledger of structural
// alternatives, all regressed or neutral: R10 smaller q-tile/2x waves
// (69.2 — LDS pipe throttles), R11 K via VMEM (70.6 — barrier drains vmcnt),
// R12 full dbuf + 1 barrier/tile + QK/PV software pipeline (62.3 — neutral),
// R13 zero-LDS register pipeline (77.2 — VMEM latency exposed at 4 waves/CU).
// The structure is balanced: exp VALU floor ~27us, LDS ~15us, MFMA ~17us
// with 2 waves/SIMD overlap. Do not re-open without a new mechanism.
#define KST 40   // Ks row stride (ushorts)
#define VTST 72  // Vts row stride (ushorts)

__global__ __launch_bounds__(256) void attn_mfma(
    const ushort_t* __restrict__ qb, const ushort_t* __restrict__ kb,
    const ushort_t* __restrict__ vtb, ushort_t* __restrict__ ao) {
  __shared__ ushort_t Ks[64 * KST];
  __shared__ ushort_t Vts[32 * VTST];
  int qt = blockIdx.x, head = blockIdx.y;
  int t = threadIdx.x;
  int w = t >> 6, lane = t & 63;
  int g = lane >> 4, c = lane & 15;
  const size_t hbase = (size_t)head * (N_TOK * DH);
  int q0 = qt * 128 + w * 32;

  short8 qf[2];
  qf[0] = *(const short8*)(qb + hbase + (size_t)(q0 + c) * DH + g * 8);
  qf[1] = *(const short8*)(qb + hbase + (size_t)(q0 + 16 + c) * DH + g * 8);

  short8 ones;
#pragma unroll
  for (int i = 0; i < 8; ++i) ones[i] = (short)0x3F80;

  f32x4 o[2][2] = {};
  f32x4 lf[2] = {};
  const f32x4 zf = {0.f, 0.f, 0.f, 0.f};

  const ushort_t* kg = kb + hbase + (size_t)(t >> 2) * DH + (t & 3) * 8;
  const ushort_t* vg = vtb + hbase + (size_t)(t >> 3) * N_TOK + (t & 7) * 8;
  ushort_t* kw = &Ks[(t >> 2) * KST + (t & 3) * 8];
  ushort_t* vw = &Vts[(t >> 3) * VTST + (t & 7) * 8];

  short8 kreg = *(const short8*)kg;
  short8 vreg = *(const short8*)vg;

  typedef union { short8 s8; unsigned int u32[4]; } pk_t;

  for (int tile = 0; tile < N_TOK / 64; ++tile) {
    __syncthreads();
    *(short8*)kw = kreg;
    *(short8*)vw = vreg;
    __syncthreads();
    if (tile + 1 < N_TOK / 64) {
      kreg = *(const short8*)(kg + (size_t)(tile + 1) * 64 * DH);
      vreg = *(const short8*)(vg + (tile + 1) * 64);
    }

    short8 kf[4];
#pragma unroll
    for (int mi = 0; mi < 4; ++mi)
      kf[mi] = *(const short8*)&Ks[(mi * 16 + c) * KST + g * 8];
    short8 vf[2][2];
#pragma unroll
    for (int half = 0; half < 2; ++half)
#pragma unroll
      for (int ch = 0; ch < 2; ++ch)
        vf[half][ch] = *(const short8*)&Vts[(half * 16 + c) * VTST + ch * 32 + g * 8];

    short8 pf[2][2];
#pragma unroll
    for (int qs = 0; qs < 2; ++qs) {
      f32x4 sp[4];
#pragma unroll
      for (int mi = 0; mi < 4; ++mi)
        sp[mi] = __builtin_amdgcn_mfma_f32_16x16x32_bf16(kf[mi], qf[qs], zf, 0, 0, 0);
      float pr[4][4];
#pragma unroll
      for (int mi = 0; mi < 4; ++mi)
#pragma unroll
        for (int r = 0; r < 4; ++r) pr[mi][r] = EXP2F(sp[mi][r]);
      pk_t p0, p1;
      p0.u32[0] = bfpack(pr[0][0], pr[0][1]);
      p0.u32[1] = bfpack(pr[0][2], pr[0][3]);
      p0.u32[2] = bfpack(pr[2][0], pr[2][1]);
      p0.u32[3] = bfpack(pr[2][2], pr[2][3]);
      p1.u32[0] = bfpack(pr[1][0], pr[1][1]);
      p1.u32[1] = bfpack(pr[1][2], pr[1][3]);
      p1.u32[2] = bfpack(pr[3][0], pr[3][1]);
      p1.u32[3] = bfpack(pr[3][2], pr[3][3]);
      pf[qs][0] = p0.s8;
      pf[qs][1] = p1.s8;
    }

#pragma unroll
    for (int qs = 0; qs < 2; ++qs) {
#pragma unroll
      for (int ch = 0; ch < 2; ++ch) {
        lf[qs] = __builtin_amdgcn_mfma_f32_16x16x32_bf16(ones, pf[qs][ch], lf[qs], 0, 0, 0);
#pragma unroll
        for (int half = 0; half < 2; ++half)
          o[qs][half] = __builtin_amdgcn_mfma_f32_16x16x32_bf16(
              vf[half][ch], pf[qs][ch], o[qs][half], 0, 0, 0);
      }
    }
  }

#pragma unroll
  for (int qs = 0; qs < 2; ++qs) {
    float inv = 1.0f / lf[qs][0];
    int q = q0 + qs * 16 + c;
    ushort_t* op = ao + (size_t)q * D + head * DH;
#pragma unroll
    for (int half = 0; half < 2; ++half)
#pragma unroll
      for (int reg = 0; reg < 4; ++reg)
        op[half * 16 + g * 4 + reg] = f2bf(o[qs][half][reg] * inv);
  }
}

// ------------------------- depthwise conv + next-LN ------------------------
__global__ void scatter_kernel(const int* __restrict__ coords,
                               int* __restrict__ pos2tok) {
  int n = blockIdx.x * 256 + threadIdx.x;
  if (n < N_TOK) pos2tok[coords[2 * n] * GW + coords[2 * n + 1]] = n;
}

__global__ __launch_bounds__(256) void conv_ln_kernel(
    const float* __restrict__ xin, float* __restrict__ xout,
    const float* __restrict__ ck, const float* __restrict__ cb,
    const int* __restrict__ pos2tok, const int* __restrict__ coords,
    const float* __restrict__ g, const float* __restrict__ b,
    float* __restrict__ yf, ushort_t* __restrict__ ybf) {
  int n = blockIdx.x, t = threadIdx.x;
  __shared__ int nb[9];
  if (t < 9) {
    int r = coords[2 * n], c = coords[2 * n + 1];
    int dy = t / 3 - 1, dx = t % 3 - 1;
    int rr = r + dy, cc = c + dx;
    nb[t] = (rr >= 0 && rr < GH && cc >= 0 && cc < GW) ? pos2tok[rr * GW + cc] : -1;
  }
  __syncthreads();
  float v[2];
#pragma unroll
  for (int j = 0; j < 2; ++j) {
    int ch = t + j * 256;
    float s = cb[ch];
#pragma unroll
    for (int tap = 0; tap < 9; ++tap) {
      int tok = nb[tap];
      if (tok >= 0) s = fmaf(ck[ch * 9 + tap], xin[(size_t)tok * D + ch], s);
    }
    v[j] = xin[(size_t)n * D + ch] + s;
    xout[(size_t)n * D + ch] = v[j];
  }
  float s = v[0] + v[1];
  float sq = v[0] * v[0] + v[1] * v[1];
#pragma unroll
  for (int off = 32; off > 0; off >>= 1) {
    s += __shfl_down(s, off, 64);
    sq += __shfl_down(sq, off, 64);
  }
  __shared__ float s1[4], s2[4];
  int wid = t >> 6, lane = t & 63;
  if (lane == 0) { s1[wid] = s; s2[wid] = sq; }
  __syncthreads();
  float tot = s1[0] + s1[1] + s1[2] + s1[3];
  float totq = s2[0] + s2[1] + s2[2] + s2[3];
  float mean = tot * (1.0f / D);
  float var = totq * (1.0f / D) - mean * mean;
  float rs = rsqrtf(var + 1e-5f);
  float r0 = (v[0] - mean) * rs * g[t] + b[t];
  float r1 = (v[1] - mean) * rs * g[t + 256] + b[t + 256];
  if (yf) { yf[(size_t)n * D + t] = r0; yf[(size_t)n * D + t + 256] = r1; }
  ybf[(size_t)n * D + t] = f2bf(r0);
  ybf[(size_t)n * D + t + 256] = f2bf(r1);
}

// ------------------------ weight cast (fp32->bf16, pad) --------------------
__global__ __launch_bounds__(256) void castw(const float* __restrict__ src,
    ushort_t* __restrict__ dst, int n_src, int n_dst) {
  int i = (blockIdx.x * 256 + threadIdx.x) * 4;
  if (i >= n_dst) return;
  unsigned long long pk = 0;
#pragma unroll
  for (int j = 0; j < 4; ++j) {
    float v = (i + j < n_src) ? src[i + j] : 0.f;
    pk |= ((unsigned long long)f2bf(v)) << (16 * j);
  }
  *(unsigned long long*)(dst + i) = pk;
}

__global__ void pad_bias(const float* __restrict__ src, float* __restrict__ dst) {
  int i = threadIdx.x;
  dst[i] = (i < GENES) ? src[i] : 0.f;
}

// ------------------------------- launch ------------------------------------
extern "C" void kernel_launch(void* const* d_in, const int* in_sizes, int n_in,
                              void* d_out, int out_size, void* d_ws, size_t ws_size,
                              hipStream_t stream) {
  const float* gf     = (const float*)d_in[0];
  const int*   coords = (const int*)d_in[1];
  const float* ln1_g  = (const float*)d_in[4];
  const float* ln1_b  = (const float*)d_in[5];
  const float* wqkv   = (const float*)d_in[6];
  const float* bqkv   = (const float*)d_in[7];
  const float* wo     = (const float*)d_in[8];
  const float* bo     = (const float*)d_in[9];
  const float* ln2_g  = (const float*)d_in[10];
  const float* ln2_b  = (const float*)d_in[11];
  const float* w1     = (const float*)d_in[12];
  const float* b1     = (const float*)d_in[13];
  const float* w2     = (const float*)d_in[14];
  const float* b2     = (const float*)d_in[15];
  const float* ck     = (const float*)d_in[16];
  const float* cb     = (const float*)d_in[17];
  const float* lnf_g  = (const float*)d_in[18];
  const float* lnf_b  = (const float*)d_in[19];
  const float* wp     = (const float*)d_in[20];
  const float* bp     = (const float*)d_in[21];
  float* out = (float*)d_out;

  const size_t ND = (size_t)N_TOK * D;
  float* xb0 = (float*)d_ws;
  float* xb1 = xb0 + ND;
  ushort_t* xn_bf  = (ushort_t*)(xb1 + ND);      // ND
  ushort_t* ao_bf  = xn_bf + ND;                 // ND
  ushort_t* out_bf = ao_bf + ND;                 // ND
  ushort_t* shared = out_bf + ND;                // max(3*ND, N*MLPD)
  ushort_t* qb   = shared;
  ushort_t* kbuf = qb + ND;
  ushort_t* vtb  = kbuf + ND;
  ushort_t* h_bf = shared;                       // aliases qkv bufs (disjoint lifetime)
  ushort_t* wqkv_bf = shared + (size_t)N_TOK * MLPD;
  ushort_t* wo_bf = wqkv_bf + DEPTH * 3 * D * D;
  ushort_t* w1_bf = wo_bf + DEPTH * D * D;
  ushort_t* w2_bf = w1_bf + DEPTH * MLPD * D;
  ushort_t* wp_bf = w2_bf + DEPTH * D * MLPD;
  float* bp_pad = (float*)(wp_bf + 256 * D);
  int* pos2tok = (int*)(bp_pad + 256);

  hipMemcpyAsync(xb0, gf, ND * sizeof(float), hipMemcpyDeviceToDevice, stream);
  hipMemsetAsync(pos2tok, 0xFF, GH * GW * sizeof(int), stream);
  scatter_kernel<<<(N_TOK + 255) / 256, 256, 0, stream>>>(coords, pos2tok);

  int nw;
  nw = DEPTH * 3 * D * D;  castw<<<(nw / 4 + 255) / 256, 256, 0, stream>>>(wqkv, wqkv_bf, nw, nw);
  nw = DEPTH * D * D;      castw<<<(nw / 4 + 255) / 256, 256, 0, stream>>>(wo, wo_bf, nw, nw);
  nw = DEPTH * MLPD * D;   castw<<<(nw / 4 + 255) / 256, 256, 0, stream>>>(w1, w1_bf, nw, nw);
  nw = DEPTH * D * MLPD;   castw<<<(nw / 4 + 255) / 256, 256, 0, stream>>>(w2, w2_bf, nw, nw);
  castw<<<(256 * D / 4 + 255) / 256, 256, 0, stream>>>(wp, wp_bf, GENES * D, 256 * D);
  pad_bias<<<1, 256, 0, stream>>>(bp, bp_pad);

  // ln1 of layer 0 (subsequent ln1/lnf are fused into conv_ln)
  ln_kernel<<<N_TOK, 256, 0, stream>>>(xb0, ln1_g, ln1_b, nullptr, xn_bf);

  float* x  = xb0;
  float* xo = xb1;
  for (int i = 0; i < DEPTH; ++i) {
    // QKV: 128x96 tile, BK=64 -> 512 blocks = 2 blocks/CU (LDS 56KB)
    gemm_bf<128, 96, 2><<<dim3(16, 32), 256, 0, stream>>>(
        xn_bf, wqkv_bf + (size_t)i * 3 * D * D, bqkv + (size_t)i * 3 * D,
        nullptr, nullptr, nullptr, qb, kbuf, vtb, D, 0, 3 * D, 2);
    attn_mfma<<<dim3(N_TOK / 128, NHEAD), 256, 0, stream>>>(qb, kbuf, vtb, ao_bf);
    gemm_bf<64, 64, 2><<<dim3(8, 64), 256, 0, stream>>>(
        ao_bf, wo_bf + (size_t)i * D * D, bo + (size_t)i * D,
        x, x, nullptr, nullptr, nullptr, nullptr, D, D, D, 0);
    ln_kernel<<<N_TOK, 256, 0, stream>>>(x, ln2_g + i * D, ln2_b + i * D, nullptr, xn_bf);
    // MLP1: 128x128 tile, BK=64 -> 512 blocks = 2 blocks/CU (LDS 64KB, cap 2)
    gemm_bf<128, 128, 2><<<dim3(16, 32), 256, 0, stream>>>(
        xn_bf, w1_bf + (size_t)i * MLPD * D, b1 + (size_t)i * MLPD,
        nullptr, nullptr, h_bf, nullptr, nullptr, nullptr, D, MLPD, MLPD, 1);
    // MLP2: 64x64 tile, BK=128 -> 512 blocks = 2 blocks/CU (LDS 64KB, cap 2)
    gemm_bf<64, 64, 4><<<dim3(8, 64), 256, 0, stream>>>(
        h_bf, w2_bf + (size_t)i * D * MLPD, b2 + (size_t)i * D,
        x, x, nullptr, nullptr, nullptr, nullptr, MLPD, D, D, 0);
    if (i < DEPTH - 1) {
      conv_ln_kernel<<<N_TOK, 256, 0, stream>>>(
          x, xo, ck + (size_t)i * D * 9, cb + (size_t)i * D, pos2tok, coords,
          ln1_g + (i + 1) * D, ln1_b + (i + 1) * D, nullptr, xn_bf);
    } else {
      conv_ln_kernel<<<N_TOK, 256, 0, stream>>>(
          x, xo, ck + (size_t)i * D * 9, cb + (size_t)i * D, pos2tok, coords,
          lnf_g, lnf_b, out, out_bf);
    }
    float* tmp = x; x = xo; xo = tmp;
  }
  gemm_bf<64, 64, 2><<<dim3(4, 64), 256, 0, stream>>>(
      out_bf, wp_bf, bp_pad, nullptr, out + ND, nullptr, nullptr, nullptr, nullptr,
      D, GENES, GENES, 0);
}

// Round 11
// 578.712 us; speedup vs baseline: 1.0807x; 1.0410x over previous
//
#include <hip/hip_runtime.h>
#include <math.h>

#define D 512
#define N_TOK 4096
#define NHEAD 16
#define DH 32
#define DEPTH 3
#define MLPD 2048
#define GENES 250
#define GH 64
#define GW 64

typedef __attribute__((ext_vector_type(8))) short short8;
typedef __attribute__((ext_vector_type(4))) float f32x4;
typedef unsigned short ushort_t;

#define AS1 __attribute__((address_space(1)))
#define AS3 __attribute__((address_space(3)))

#if defined(__has_builtin)
#if __has_builtin(__builtin_amdgcn_exp2f)
#define EXP2F(x) __builtin_amdgcn_exp2f(x)
#endif
#endif
#ifndef EXP2F
#define EXP2F(x) __expf(0.69314718056f * (x))
#endif

__device__ __forceinline__ unsigned short f2bf(float f) {
  unsigned int u = __float_as_uint(f);
  u += 0x7fffu + ((u >> 16) & 1u);
  return (unsigned short)(u >> 16);
}
__device__ __forceinline__ unsigned int bfpack(float a, float b) {
  return __builtin_amdgcn_perm(__float_as_uint(b), __float_as_uint(a), 0x07060302u);
}
__device__ __forceinline__ void gload_lds16(const ushort_t* g, ushort_t* l) {
  __builtin_amdgcn_global_load_lds(
      (const AS1 unsigned int*)g,
      (AS3 unsigned int*)(unsigned int)(unsigned long long)l, 16, 0, 0);
}
// key permutation shared by the V^T store and the attention P-fragment
__device__ __forceinline__ int perm64(int m) {
  int mi = m >> 4, g = (m >> 2) & 3, r = m & 3;
  return ((mi & 1) << 5) | (g << 3) | ((mi >> 1) << 2) | r;
}

// ------------------------------- LayerNorm --------------------------------
// R19: optional xcopy side-output fuses the initial gf->xb0 D2D memcpy into
// the first LN pass (one 8MB read pass + one dispatch saved).
__global__ __launch_bounds__(256) void ln_kernel(const float* __restrict__ x,
    const float* __restrict__ g, const float* __restrict__ b,
    float* __restrict__ yf, ushort_t* __restrict__ ybf,
    float* __restrict__ xcopy) {
  int row = blockIdx.x;
  int t = threadIdx.x;
  const float* xr = x + (size_t)row * D;
  float v0 = xr[t], v1 = xr[t + 256];
  if (xcopy) {
    xcopy[(size_t)row * D + t] = v0;
    xcopy[(size_t)row * D + t + 256] = v1;
  }
  float s = v0 + v1;
  float sq = v0 * v0 + v1 * v1;
#pragma unroll
  for (int off = 32; off > 0; off >>= 1) {
    s += __shfl_down(s, off, 64);
    sq += __shfl_down(sq, off, 64);
  }
  __shared__ float s1[4], s2[4];
  int wid = t >> 6, lane = t & 63;
  if (lane == 0) { s1[wid] = s; s2[wid] = sq; }
  __syncthreads();
  float tot = s1[0] + s1[1] + s1[2] + s1[3];
  float totq = s2[0] + s2[1] + s2[2] + s2[3];
  float mean = tot * (1.0f / D);
  float var = totq * (1.0f / D) - mean * mean;
  float rs = rsqrtf(var + 1e-5f);
  float r0 = (v0 - mean) * rs * g[t] + b[t];
  float r1 = (v1 - mean) * rs * g[t + 256] + b[t + 256];
  if (yf) { yf[(size_t)row * D + t] = r0; yf[(size_t)row * D + t + 256] = r1; }
  if (ybf) {
    ybf[(size_t)row * D + t] = f2bf(r0);
    ybf[(size_t)row * D + t + 256] = f2bf(r1);
  }
}

// ---------------------------- bf16 MFMA GEMM -------------------------------
// R7 structure (best measured): tile TMxTN, BK=32*NKH, double-buffered LDS,
// prefetch of iter k+1 issued right after the barrier releasing the buffer.
// R14 (WIN, -13us): T1 XCD-aware block swizzle (bijective, nwg%8==0).
// R15 (small win, -5us): NKH bump (barrier-drain amortization).
// R16 (WIN, -12us): MLP1 -> 128x128; GEMM ceiling = LDS read pipe
// (MFMA-per-ds_read ratio) AT CONSTANT residency.
// R17 (REGRESSED +33us, reverted): split-K atomicAdd — same-address L2 RMW
// serialization. R18 (REGRESSED +10us, reverted): QKV 128x96 — ratio gain
// (1.33->1.71) lost to residency drop (3->2 blocks/CU). Lesson: ratio
// improvements only pay at constant blocks/CU. Shape search is exhausted;
// 2-barrier-family optimum = QKV 128x64@3/CU, MLP1 128x128@2/CU,
// WO 64x64 NKH2, MLP2 64x64 NKH4.
// mode 0: fp32 C (+res). mode 1: gelu -> Cbf. mode 2: qkv routing.
template <int TM, int TN, int NKH>
__global__ __launch_bounds__(256) void gemm_bf(
    const ushort_t* __restrict__ A, const ushort_t* __restrict__ B,
    const float* __restrict__ bias, const float* __restrict__ res,
    float* __restrict__ C, ushort_t* __restrict__ Cbf,
    ushort_t* __restrict__ qO, ushort_t* __restrict__ kO, ushort_t* __restrict__ vO,
    int K, int ldc, int nstore, int mode) {
  constexpr int MI = TM / 32;
  constexpr int NI = TN / 32;
  __shared__ ushort_t As[2][NKH][TM * 32];
  __shared__ ushort_t Bs[2][NKH][TN * 32];
  int t = threadIdx.x;
  int w = t >> 6, lane = t & 63;
  int g = lane >> 4, c = lane & 15;
  // T1 XCD swizzle: work-id chunking so consecutive tiles share an XCD L2
  int orig = blockIdx.y * gridDim.x + blockIdx.x;
  int cpx = (gridDim.x * gridDim.y) >> 3;
  int wid2 = (orig & 7) * cpx + (orig >> 3);
  int bn = (wid2 % gridDim.x) * TN;
  int bm = (wid2 / gridDim.x) * TM;
  int wr = (w >> 1) * (TM / 2);
  int wc = (w & 1) * (TN / 2);

  const ushort_t* gA = A + (size_t)(bm + (t >> 2)) * K + (t & 3) * 8;
  const ushort_t* gB = B + (size_t)(bn + (t >> 2)) * K + (t & 3) * 8;

  auto stage = [&](int p, int koff) {
#pragma unroll
    for (int h = 0; h < NKH; ++h) {
      gload_lds16(gA + koff + h * 32, &As[p][h][t * 8]);
      if (TM == 128)
        gload_lds16(gA + koff + h * 32 + (size_t)64 * K, &As[p][h][(t + 256) * 8]);
      gload_lds16(gB + koff + h * 32, &Bs[p][h][t * 8]);
      if (TN == 128)
        gload_lds16(gB + koff + h * 32 + (size_t)64 * K, &Bs[p][h][(t + 256) * 8]);
    }
  };

  f32x4 acc[MI][NI] = {};

  const int niter = K / (32 * NKH);
  stage(0, 0);
  __syncthreads();
  for (int it = 0; it < niter; ++it) {
    int p = it & 1;
    if (it + 1 < niter) stage(p ^ 1, (it + 1) * 32 * NKH);  // prefetch overlaps compute
#pragma unroll
    for (int kh = 0; kh < NKH; ++kh) {
      short8 af[MI], bfr[NI];
#pragma unroll
      for (int mi = 0; mi < MI; ++mi)
        af[mi] = *(const short8*)&As[p][kh][(wr + mi * 16 + c) * 32 + g * 8];
#pragma unroll
      for (int ni = 0; ni < NI; ++ni)
        bfr[ni] = *(const short8*)&Bs[p][kh][(wc + ni * 16 + c) * 32 + g * 8];
#pragma unroll
      for (int mi = 0; mi < MI; ++mi)
#pragma unroll
        for (int ni = 0; ni < NI; ++ni)
          acc[mi][ni] = __builtin_amdgcn_mfma_f32_16x16x32_bf16(
              af[mi], bfr[ni], acc[mi][ni], 0, 0, 0);
    }
    __syncthreads();
  }

  const float qs_scale = 0.17677669529663688f * 1.4426950408889634f;
  if (mode == 2) {
#pragma unroll
    for (int ni = 0; ni < NI; ++ni) {
      int col = bn + wc + ni * 16 + c;
      float bv = bias[col];
      int which = col >> 9;
      int h = (col >> 5) & 15;
      int d = col & 31;
      size_t hb = (size_t)h * (N_TOK * DH);
#pragma unroll
      for (int mi = 0; mi < MI; ++mi) {
        int row0 = bm + wr + mi * 16 + g * 4;
        float v0 = acc[mi][ni][0] + bv;
        float v1 = acc[mi][ni][1] + bv;
        float v2 = acc[mi][ni][2] + bv;
        float v3 = acc[mi][ni][3] + bv;
        if (which == 0) {
          qO[hb + (size_t)(row0 + 0) * DH + d] = f2bf(v0 * qs_scale);
          qO[hb + (size_t)(row0 + 1) * DH + d] = f2bf(v1 * qs_scale);
          qO[hb + (size_t)(row0 + 2) * DH + d] = f2bf(v2 * qs_scale);
          qO[hb + (size_t)(row0 + 3) * DH + d] = f2bf(v3 * qs_scale);
        } else if (which == 1) {
          kO[hb + (size_t)(row0 + 0) * DH + d] = f2bf(v0);
          kO[hb + (size_t)(row0 + 1) * DH + d] = f2bf(v1);
          kO[hb + (size_t)(row0 + 2) * DH + d] = f2bf(v2);
          kO[hb + (size_t)(row0 + 3) * DH + d] = f2bf(v3);
        } else {
          int m = row0 & 63;
          int mi_l = m >> 4, g_l = (m >> 2) & 3;
          int nb = ((mi_l & 1) << 5) | (g_l << 3) | ((mi_l >> 1) << 2);
          uint2 pk;
          pk.x = (unsigned)f2bf(v0) | ((unsigned)f2bf(v1) << 16);
          pk.y = (unsigned)f2bf(v2) | ((unsigned)f2bf(v3) << 16);
          *(uint2*)(vO + hb + (size_t)d * N_TOK + (row0 & ~63) + nb) = pk;
        }
      }
    }
    return;
  }
#pragma unroll
  for (int ni = 0; ni < NI; ++ni) {
    int col = bn + wc + ni * 16 + c;
    float bv = bias[col];
    bool cok = col < nstore;
#pragma unroll
    for (int mi = 0; mi < MI; ++mi) {
      int row0 = bm + wr + mi * 16 + g * 4;
#pragma unroll
      for (int reg = 0; reg < 4; ++reg) {
        int row = row0 + reg;
        float v = acc[mi][ni][reg] + bv;
        if (mode == 0) {
          size_t idx = (size_t)row * ldc + col;
          if (cok) {
            if (res) v += res[idx];
            C[idx] = v;
          }
        } else {
          v = 0.5f * v * (1.0f + erff(v * 0.70710678118654752f));
          Cbf[(size_t)row * ldc + col] = f2bf(v);
        }
      }
    }
  }
}

// --------------------------- MFMA flash attention --------------------------
// R7 version verbatim (proven best: ~62 us/layer). Ledger of structural
// alternatives, all regressed or neutral: R10 smaller q-tile/2x waves
// (69.2 — LDS pipe throttles), R11 K via VMEM (70.6 — barrier drains vmcnt),
// R12 full dbuf + 1 barrier/tile + QK/PV software pipeline (62.3 — neutral),
// R13 zero-LDS register pipeline (77.2 — VMEM latency exposed at 4 waves/CU).
// The structure is balanced: exp VALU floor ~27us, LDS ~15us, MFMA ~17us
// with 2 waves/SIMD overlap. Do not re-open without a new mechanism.
#define KST 40   // Ks row stride (ushorts)
#define VTST 72  // Vts row stride (ushorts)

__global__ __launch_bounds__(256) void attn_mfma(
    const ushort_t* __restrict__ qb, const ushort_t* __restrict__ kb,
    const ushort_t* __restrict__ vtb, ushort_t* __restrict__ ao) {
  __shared__ ushort_t Ks[64 * KST];
  __shared__ ushort_t Vts[32 * VTST];
  int qt = blockIdx.x, head = blockIdx.y;
  int t = threadIdx.x;
  int w = t >> 6, lane = t & 63;
  int g = lane >> 4, c = lane & 15;
  const size_t hbase = (size_t)head * (N_TOK * DH);
  int q0 = qt * 128 + w * 32;

  short8 qf[2];
  qf[0] = *(const short8*)(qb + hbase + (size_t)(q0 + c) * DH + g * 8);
  qf[1] = *(const short8*)(qb + hbase + (size_t)(q0 + 16 + c) * DH + g * 8);

  short8 ones;
#pragma unroll
  for (int i = 0; i < 8; ++i) ones[i] = (short)0x3F80;

  f32x4 o[2][2] = {};
  f32x4 lf[2] = {};
  const f32x4 zf = {0.f, 0.f, 0.f, 0.f};

  const ushort_t* kg = kb + hbase + (size_t)(t >> 2) * DH + (t & 3) * 8;
  const ushort_t* vg = vtb + hbase + (size_t)(t >> 3) * N_TOK + (t & 7) * 8;
  ushort_t* kw = &Ks[(t >> 2) * KST + (t & 3) * 8];
  ushort_t* vw = &Vts[(t >> 3) * VTST + (t & 7) * 8];

  short8 kreg = *(const short8*)kg;
  short8 vreg = *(const short8*)vg;

  typedef union { short8 s8; unsigned int u32[4]; } pk_t;

  for (int tile = 0; tile < N_TOK / 64; ++tile) {
    __syncthreads();
    *(short8*)kw = kreg;
    *(short8*)vw = vreg;
    __syncthreads();
    if (tile + 1 < N_TOK / 64) {
      kreg = *(const short8*)(kg + (size_t)(tile + 1) * 64 * DH);
      vreg = *(const short8*)(vg + (tile + 1) * 64);
    }

    short8 kf[4];
#pragma unroll
    for (int mi = 0; mi < 4; ++mi)
      kf[mi] = *(const short8*)&Ks[(mi * 16 + c) * KST + g * 8];
    short8 vf[2][2];
#pragma unroll
    for (int half = 0; half < 2; ++half)
#pragma unroll
      for (int ch = 0; ch < 2; ++ch)
        vf[half][ch] = *(const short8*)&Vts[(half * 16 + c) * VTST + ch * 32 + g * 8];

    short8 pf[2][2];
#pragma unroll
    for (int qs = 0; qs < 2; ++qs) {
      f32x4 sp[4];
#pragma unroll
      for (int mi = 0; mi < 4; ++mi)
        sp[mi] = __builtin_amdgcn_mfma_f32_16x16x32_bf16(kf[mi], qf[qs], zf, 0, 0, 0);
      float pr[4][4];
#pragma unroll
      for (int mi = 0; mi < 4; ++mi)
#pragma unroll
        for (int r = 0; r < 4; ++r) pr[mi][r] = EXP2F(sp[mi][r]);
      pk_t p0, p1;
      p0.u32[0] = bfpack(pr[0][0], pr[0][1]);
      p0.u32[1] = bfpack(pr[0][2], pr[0][3]);
      p0.u32[2] = bfpack(pr[2][0], pr[2][1]);
      p0.u32[3] = bfpack(pr[2][2], pr[2][3]);
      p1.u32[0] = bfpack(pr[1][0], pr[1][1]);
      p1.u32[1] = bfpack(pr[1][2], pr[1][3]);
      p1.u32[2] = bfpack(pr[3][0], pr[3][1]);
      p1.u32[3] = bfpack(pr[3][2], pr[3][3]);
      pf[qs][0] = p0.s8;
      pf[qs][1] = p1.s8;
    }

#pragma unroll
    for (int qs = 0; qs < 2; ++qs) {
#pragma unroll
      for (int ch = 0; ch < 2; ++ch) {
        lf[qs] = __builtin_amdgcn_mfma_f32_16x16x32_bf16(ones, pf[qs][ch], lf[qs], 0, 0, 0);
#pragma unroll
        for (int half = 0; half < 2; ++half)
          o[qs][half] = __builtin_amdgcn_mfma_f32_16x16x32_bf16(
              vf[half][ch], pf[qs][ch], o[qs][half], 0, 0, 0);
      }
    }
  }

#pragma unroll
  for (int qs = 0; qs < 2; ++qs) {
    float inv = 1.0f / lf[qs][0];
    int q = q0 + qs * 16 + c;
    ushort_t* op = ao + (size_t)q * D + head * DH;
#pragma unroll
    for (int half = 0; half < 2; ++half)
#pragma unroll
      for (int reg = 0; reg < 4; ++reg)
        op[half * 16 + g * 4 + reg] = f2bf(o[qs][half][reg] * inv);
  }
}

// ------------------------- depthwise conv + next-LN ------------------------
// R19: pos2tok memset dropped — coords is a permutation of ALL GH*GW=4096
// cells (N_TOK == GH*GW), so scatter fully initializes the map.
__global__ void scatter_kernel(const int* __restrict__ coords,
                               int* __restrict__ pos2tok) {
  int n = blockIdx.x * 256 + threadIdx.x;
  if (n < N_TOK) pos2tok[coords[2 * n] * GW + coords[2 * n + 1]] = n;
}

__global__ __launch_bounds__(256) void conv_ln_kernel(
    const float* __restrict__ xin, float* __restrict__ xout,
    const float* __restrict__ ck, const float* __restrict__ cb,
    const int* __restrict__ pos2tok, const int* __restrict__ coords,
    const float* __restrict__ g, const float* __restrict__ b,
    float* __restrict__ yf, ushort_t* __restrict__ ybf) {
  int n = blockIdx.x, t = threadIdx.x;
  __shared__ int nb[9];
  if (t < 9) {
    int r = coords[2 * n], c = coords[2 * n + 1];
    int dy = t / 3 - 1, dx = t % 3 - 1;
    int rr = r + dy, cc = c + dx;
    nb[t] = (rr >= 0 && rr < GH && cc >= 0 && cc < GW) ? pos2tok[rr * GW + cc] : -1;
  }
  __syncthreads();
  float v[2];
#pragma unroll
  for (int j = 0; j < 2; ++j) {
    int ch = t + j * 256;
    float s = cb[ch];
#pragma unroll
    for (int tap = 0; tap < 9; ++tap) {
      int tok = nb[tap];
      if (tok >= 0) s = fmaf(ck[ch * 9 + tap], xin[(size_t)tok * D + ch], s);
    }
    v[j] = xin[(size_t)n * D + ch] + s;
    xout[(size_t)n * D + ch] = v[j];
  }
  float s = v[0] + v[1];
  float sq = v[0] * v[0] + v[1] * v[1];
#pragma unroll
  for (int off = 32; off > 0; off >>= 1) {
    s += __shfl_down(s, off, 64);
    sq += __shfl_down(sq, off, 64);
  }
  __shared__ float s1[4], s2[4];
  int wid = t >> 6, lane = t & 63;
  if (lane == 0) { s1[wid] = s; s2[wid] = sq; }
  __syncthreads();
  float tot = s1[0] + s1[1] + s1[2] + s1[3];
  float totq = s2[0] + s2[1] + s2[2] + s2[3];
  float mean = tot * (1.0f / D);
  float var = totq * (1.0f / D) - mean * mean;
  float rs = rsqrtf(var + 1e-5f);
  float r0 = (v[0] - mean) * rs * g[t] + b[t];
  float r1 = (v[1] - mean) * rs * g[t + 256] + b[t + 256];
  if (yf) { yf[(size_t)n * D + t] = r0; yf[(size_t)n * D + t + 256] = r1; }
  ybf[(size_t)n * D + t] = f2bf(r0);
  ybf[(size_t)n * D + t + 256] = f2bf(r1);
}

// ------------------ fused weight cast (fp32->bf16, all segs) ---------------
// R19: one kernel replaces 5 castw + pad_bias. Dst segments are contiguous
// in ws (wqkv|wo|w1|w2|wp); boundaries are compile-time, all %4==0 so no
// 4-group straddles. Last block handles bp padding.
#define CS0 (DEPTH * 3 * D * D)
#define CS1 (DEPTH * D * D)
#define CS2 (DEPTH * MLPD * D)
#define CS3 (DEPTH * D * MLPD)
#define CS4 (256 * D)
#define CT0 (CS0)
#define CT1 (CT0 + CS1)
#define CT2 (CT1 + CS2)
#define CT3 (CT2 + CS3)
#define CT4 (CT3 + CS4)
#define NB_CAST (CT4 / 4 / 256)  // 9344 blocks of casting work

__global__ __launch_bounds__(256) void castw_all(
    const float* __restrict__ wqkv, const float* __restrict__ wo,
    const float* __restrict__ w1, const float* __restrict__ w2,
    const float* __restrict__ wp, const float* __restrict__ bp,
    ushort_t* __restrict__ dst, float* __restrict__ bp_pad) {
  if (blockIdx.x == NB_CAST) {  // tail block: pad_bias
    int i = threadIdx.x;
    bp_pad[i] = (i < GENES) ? bp[i] : 0.f;
    return;
  }
  int i = (blockIdx.x * 256 + threadIdx.x) * 4;
  const float* src;
  int si, ns;
  if (i < CT0)      { src = wqkv; si = i;       ns = CS0; }
  else if (i < CT1) { src = wo;   si = i - CT0; ns = CS1; }
  else if (i < CT2) { src = w1;   si = i - CT1; ns = CS2; }
  else if (i < CT3) { src = w2;   si = i - CT2; ns = CS3; }
  else              { src = wp;   si = i - CT3; ns = GENES * D; }
  unsigned long long pk = 0;
#pragma unroll
  for (int j = 0; j < 4; ++j) {
    float v = (si + j < ns) ? src[si + j] : 0.f;
    pk |= ((unsigned long long)f2bf(v)) << (16 * j);
  }
  *(unsigned long long*)(dst + i) = pk;
}

// ------------------------------- launch ------------------------------------
extern "C" void kernel_launch(void* const* d_in, const int* in_sizes, int n_in,
                              void* d_out, int out_size, void* d_ws, size_t ws_size,
                              hipStream_t stream) {
  const float* gf     = (const float*)d_in[0];
  const int*   coords = (const int*)d_in[1];
  const float* ln1_g  = (const float*)d_in[4];
  const float* ln1_b  = (const float*)d_in[5];
  const float* wqkv   = (const float*)d_in[6];
  const float* bqkv   = (const float*)d_in[7];
  const float* wo     = (const float*)d_in[8];
  const float* bo     = (const float*)d_in[9];
  const float* ln2_g  = (const float*)d_in[10];
  const float* ln2_b  = (const float*)d_in[11];
  const float* w1     = (const float*)d_in[12];
  const float* b1     = (const float*)d_in[13];
  const float* w2     = (const float*)d_in[14];
  const float* b2     = (const float*)d_in[15];
  const float* ck     = (const float*)d_in[16];
  const float* cb     = (const float*)d_in[17];
  const float* lnf_g  = (const float*)d_in[18];
  const float* lnf_b  = (const float*)d_in[19];
  const float* wp     = (const float*)d_in[20];
  const float* bp     = (const float*)d_in[21];
  float* out = (float*)d_out;

  const size_t ND = (size_t)N_TOK * D;
  float* xb0 = (float*)d_ws;
  float* xb1 = xb0 + ND;
  ushort_t* xn_bf  = (ushort_t*)(xb1 + ND);      // ND
  ushort_t* ao_bf  = xn_bf + ND;                 // ND
  ushort_t* out_bf = ao_bf + ND;                 // ND
  ushort_t* shared = out_bf + ND;                // max(3*ND, N*MLPD)
  ushort_t* qb   = shared;
  ushort_t* kbuf = qb + ND;
  ushort_t* vtb  = kbuf + ND;
  ushort_t* h_bf = shared;                       // aliases qkv bufs (disjoint lifetime)
  ushort_t* wqkv_bf = shared + (size_t)N_TOK * MLPD;
  ushort_t* wo_bf = wqkv_bf + DEPTH * 3 * D * D;
  ushort_t* w1_bf = wo_bf + DEPTH * D * D;
  ushort_t* w2_bf = w1_bf + DEPTH * MLPD * D;
  ushort_t* wp_bf = w2_bf + DEPTH * D * MLPD;
  float* bp_pad = (float*)(wp_bf + 256 * D);
  int* pos2tok = (int*)(bp_pad + 256);

  // pos2tok: coords is a permutation of all GH*GW==N_TOK cells -> scatter
  // fully initializes it; no memset needed.
  scatter_kernel<<<(N_TOK + 255) / 256, 256, 0, stream>>>(coords, pos2tok);

  // all weight casts + bias pad in ONE dispatch (dst segments contiguous)
  castw_all<<<NB_CAST + 1, 256, 0, stream>>>(
      wqkv, wo, w1, w2, wp, bp, wqkv_bf, bp_pad);

  // ln1 of layer 0, fused with the gf->xb0 copy
  ln_kernel<<<N_TOK, 256, 0, stream>>>(gf, ln1_g, ln1_b, nullptr, xn_bf, xb0);

  float* x  = xb0;
  float* xo = xb1;
  for (int i = 0; i < DEPTH; ++i) {
    // QKV: 128x64 tile, BK=64 -> 768 blocks = 3 blocks/CU (LDS 48KB)
    gemm_bf<128, 64, 2><<<dim3(24, 32), 256, 0, stream>>>(
        xn_bf, wqkv_bf + (size_t)i * 3 * D * D, bqkv + (size_t)i * 3 * D,
        nullptr, nullptr, nullptr, qb, kbuf, vtb, D, 0, 3 * D, 2);
    attn_mfma<<<dim3(N_TOK / 128, NHEAD), 256, 0, stream>>>(qb, kbuf, vtb, ao_bf);
    gemm_bf<64, 64, 2><<<dim3(8, 64), 256, 0, stream>>>(
        ao_bf, wo_bf + (size_t)i * D * D, bo + (size_t)i * D,
        x, x, nullptr, nullptr, nullptr, nullptr, D, D, D, 0);
    ln_kernel<<<N_TOK, 256, 0, stream>>>(x, ln2_g + i * D, ln2_b + i * D,
                                         nullptr, xn_bf, nullptr);
    // MLP1: 128x128 tile, BK=64 -> 512 blocks = 2 blocks/CU (LDS 64KB, cap 2)
    gemm_bf<128, 128, 2><<<dim3(16, 32), 256, 0, stream>>>(
        xn_bf, w1_bf + (size_t)i * MLPD * D, b1 + (size_t)i * MLPD,
        nullptr, nullptr, h_bf, nullptr, nullptr, nullptr, D, MLPD, MLPD, 1);
    // MLP2: 64x64 tile, BK=128 -> 512 blocks = 2 blocks/CU (LDS 64KB, cap 2)
    gemm_bf<64, 64, 4><<<dim3(8, 64), 256, 0, stream>>>(
        h_bf, w2_bf + (size_t)i * D * MLPD, b2 + (size_t)i * D,
        x, x, nullptr, nullptr, nullptr, nullptr, MLPD, D, D, 0);
    if (i < DEPTH - 1) {
      conv_ln_kernel<<<N_TOK, 256, 0, stream>>>(
          x, xo, ck + (size_t)i * D * 9, cb + (size_t)i * D, pos2tok, coords,
          ln1_g + (i + 1) * D, ln1_b + (i + 1) * D, nullptr, xn_bf);
    } else {
      conv_ln_kernel<<<N_TOK, 256, 0, stream>>>(
          x, xo, ck + (size_t)i * D * 9, cb + (size_t)i * D, pos2tok, coords,
          lnf_g, lnf_b, out, out_bf);
    }
    float* tmp = x; x = xo; xo = tmp;
  }
  gemm_bf<64, 64, 2><<<dim3(4, 64), 256, 0, stream>>>(
      out_bf, wp_bf, bp_pad, nullptr, out + ND, nullptr, nullptr, nullptr, nullptr,
      D, GENES, GENES, 0);
}